// Round 4
// baseline (506.387 us; speedup 1.0000x reference)
//
#include <hip/hip_runtime.h>

#define HWSZ 65536   // 256*256
#define CCH  64

typedef __bf16 bf16x8 __attribute__((ext_vector_type(8)));
typedef float  f32x4  __attribute__((ext_vector_type(4)));

// ---------------------------------------------------------------------------
// Weight prep: f32 src [OC][64][KK] -> bf16 dst laid out so a wave's 64 lanes
// load an A-fragment as one contiguous 1KB segment:
//   dst[ ((k*MF + m)*2 + ks)*64 + lane ] (bf16x8)  <->
//   W[k][o = m*16 + (lane&15)][i = ks*32 + (lane>>4)*8 + j]
// ---------------------------------------------------------------------------
template<int KK, int OC>
__global__ __launch_bounds__(256) void k_prep(
    const float* __restrict__ src, __bf16* __restrict__ dst)
{
    constexpr int MF = (OC == 9) ? 1 : 4;
    int t = blockIdx.x * 256 + threadIdx.x;
    if (t >= KK * MF * 1024) return;
    int j    = t & 7;
    int lane = (t >> 3) & 63;
    int ks   = (t >> 9) & 1;
    int m    = (t >> 10) % MF;
    int k    = t / (MF * 1024);
    int o    = m * 16 + (lane & 15);
    int i    = ks * 32 + (lane >> 4) * 8 + j;
    float v  = (o < OC) ? src[((size_t)o * 64 + i) * KK + k] : 0.f;
    dst[t] = (__bf16)v;
}

// ---------------------------------------------------------------------------
// MFMA implicit-GEMM conv. Block = 16x16 pixel tile, 4 waves; wave computes
// M = MF*16 out-ch x 64 pixels via mfma_f32_16x16x32_bf16.
// x-tile staged ONCE in LDS ([pix][64ch] bf16, XOR-swizzled 16B slots);
// A-fragments read directly from global (L1/L2-resident, coalesced 1KB
// segments), double-buffered by unroll parity. NO in-loop barriers.
// ---------------------------------------------------------------------------
template<int KSZ, int MF, int RELU>
__global__ __launch_bounds__(256) void k_mconv(
    const float* __restrict__ x, const __bf16* __restrict__ wb,
    const float* __restrict__ bias, float* __restrict__ out)
{
    constexpr int PAD   = KSZ / 2;
    constexpr int TW    = 16 + 2 * PAD;     // 18 or 20
    constexpr int NPIX  = TW * TW;          // 324 or 400
    constexpr int KK    = KSZ * KSZ;        // 9 or 25
    constexpr int OUTC  = (MF == 1) ? 9 : 64;

    __shared__ __align__(16) __bf16 lx[NPIX * 64];   // swizzled 128-B rows
    __shared__ float lb[64];

    const int t    = threadIdx.x;
    const int w0   = blockIdx.x * 16, h0 = blockIdx.y * 16, b = blockIdx.z;
    const int wvv  = t >> 6;
    const int lane = t & 63;
    const int px   = lane & 15;       // A-row / B-col selector
    const int g    = lane >> 4;       // k-group 0..3

    if (t < 64) lb[t] = (t < OUTC) ? bias[t] : 0.f;

    // ---- stage x tile: global f32 [c][gy][gx] -> LDS bf16 [pix][c] swizzled
    const float* xb = x + (size_t)b * CCH * HWSZ;
    for (int e = t; e < NPIX * 64; e += 256) {
        int c   = e / NPIX;
        int pix = e - c * NPIX;
        int sy  = pix / TW, sx = pix - sy * TW;
        int gy  = h0 + sy - PAD, gx = w0 + sx - PAD;
        float v = 0.f;
        if ((unsigned)gy < 256u && (unsigned)gx < 256u)
            v = xb[(size_t)c * HWSZ + gy * 256 + gx];
        int byteoff = (pix << 7) + (((c << 1)) ^ ((pix & 7) << 4));
        *(__bf16*)((char*)lx + byteoff) = (__bf16)v;
    }
    __syncthreads();   // the only barrier

    f32x4 acc[MF][4];
    #pragma unroll
    for (int m = 0; m < MF; ++m)
        #pragma unroll
        for (int nf = 0; nf < 4; ++nf)
            acc[m][nf] = (f32x4){0.f, 0.f, 0.f, 0.f};

    const bf16x8* wv8 = (const bf16x8*)wb;

    auto LOADA = [&](int k, bf16x8 (&af)[MF][2]) {
        #pragma unroll
        for (int m = 0; m < MF; ++m)
            #pragma unroll
            for (int ks = 0; ks < 2; ++ks)
                af[m][ks] = wv8[((k * MF + m) * 2 + ks) * 64 + lane];
    };
    auto LOADB = [&](int k, bf16x8 (&bf)[4][2]) {
        int dy = k / KSZ, dx = k - dy * KSZ;
        #pragma unroll
        for (int nf = 0; nf < 4; ++nf) {
            int pix = (wvv * 4 + nf + dy) * TW + (px + dx);
            int rowbase = pix << 7, sw = (pix & 7) << 4;
            #pragma unroll
            for (int ks = 0; ks < 2; ++ks)
                bf[nf][ks] = *(const bf16x8*)((const char*)lx + rowbase + ((((ks * 4 + g) << 4)) ^ sw));
        }
    };
    auto MFMAS = [&](bf16x8 (&af)[MF][2], bf16x8 (&bf)[4][2]) {
        #pragma unroll
        for (int m = 0; m < MF; ++m)
            #pragma unroll
            for (int nf = 0; nf < 4; ++nf)
                #pragma unroll
                for (int ks = 0; ks < 2; ++ks)
                    acc[m][nf] = __builtin_amdgcn_mfma_f32_16x16x32_bf16(
                        af[m][ks], bf[nf][ks], acc[m][nf], 0, 0, 0);
    };

    bf16x8 aA[MF][2], bA[4][2], aB[MF][2], bB[4][2];
    LOADA(0, aA); LOADB(0, bA);
    #pragma unroll
    for (int k = 0; k < KK; ++k) {
        if ((k & 1) == 0) {
            if (k + 1 < KK) { LOADA(k + 1, aB); LOADB(k + 1, bB); }
            MFMAS(aA, bA);
        } else {
            if (k + 1 < KK) { LOADA(k + 1, aA); LOADB(k + 1, bA); }
            MFMAS(aB, bB);
        }
    }

    // ---- epilogue: D row = g*4+j (+16*m), col = px
    float* ob = out + (size_t)b * OUTC * HWSZ;
    #pragma unroll
    for (int m = 0; m < MF; ++m)
        #pragma unroll
        for (int nf = 0; nf < 4; ++nf) {
            int row = h0 + wvv * 4 + nf, col = w0 + px;
            #pragma unroll
            for (int j = 0; j < 4; ++j) {
                int o = m * 16 + g * 4 + j;
                if (o < OUTC) {
                    float v = acc[m][nf][j] + lb[o];
                    if (RELU) v = v > 0.f ? v : 0.01f * v;
                    ob[(size_t)o * HWSZ + row * 256 + col] = v;
                }
            }
        }
}

// ---------------------------------------------------------------------------
// 1x1 conv (residual), f32 (memory-bound).
// ---------------------------------------------------------------------------
__global__ __launch_bounds__(256) void k_conv1x1(
    const float* __restrict__ x, const float* __restrict__ w,
    const float* __restrict__ bias, float* __restrict__ out)
{
    __shared__ __align__(16) float lwT[4096];   // [i][o]
    __shared__ float lb[64];
    int t = threadIdx.x;
    for (int s = t; s < 4096; s += 256) lwT[s] = w[(s & 63) * 64 + (s >> 6)];
    if (t < 64) lb[t] = bias[t];
    __syncthreads();

    int p  = blockIdx.x * 256 + t;
    int b  = p >> 16, hw = p & 65535;
    const float* xp = x + (size_t)b * CCH * HWSZ + hw;

    float acc[64];
    #pragma unroll
    for (int o = 0; o < 64; ++o) acc[o] = lb[o];

    #pragma unroll 4
    for (int i = 0; i < 64; ++i) {
        float xi = xp[(size_t)i * HWSZ];
        const float4* w4 = (const float4*)&lwT[i * 64];
        #pragma unroll
        for (int o4 = 0; o4 < 16; ++o4) {
            float4 wv = w4[o4];
            acc[o4*4+0] += wv.x * xi;
            acc[o4*4+1] += wv.y * xi;
            acc[o4*4+2] += wv.z * xi;
            acc[o4*4+3] += wv.w * xi;
        }
    }
    float* op = out + (size_t)b * CCH * HWSZ + hw;
    #pragma unroll
    for (int o = 0; o < 64; ++o) op[(size_t)o * HWSZ] = acc[o];
}

// ---------------------------------------------------------------------------
// Adaptive einsum (+ optional in-place residual add), f32 (memory-bound).
// ---------------------------------------------------------------------------
template<int ADDRES>
__global__ __launch_bounds__(256) void k_ada(
    const float* __restrict__ wgt, const float* __restrict__ xin,
    float* __restrict__ out)
{
    int p  = blockIdx.x * 256 + threadIdx.x;
    int b  = p >> 16, hw = p & 65535;
    int h  = hw >> 8, wc = hw & 255;

    const float* wp = wgt + (size_t)b * 9 * HWSZ + hw;
    float wk[9];
    #pragma unroll
    for (int k = 0; k < 9; ++k) wk[k] = wp[(size_t)k * HWSZ];

    bool oky[3], okx[3];
    #pragma unroll
    for (int d = 0; d < 3; ++d) {
        oky[d] = (unsigned)(h  + d - 1) < 256u;
        okx[d] = (unsigned)(wc + d - 1) < 256u;
    }

    const float* xb = xin + (size_t)b * CCH * HWSZ;
    float*       ob = out + (size_t)b * CCH * HWSZ;

    for (int c = 0; c < 64; ++c) {
        const float* xc = xb + (size_t)c * HWSZ;
        float s = 0.f;
        #pragma unroll
        for (int dy = 0; dy < 3; ++dy)
            #pragma unroll
            for (int dx = 0; dx < 3; ++dx) {
                float v = (oky[dy] && okx[dx]) ? xc[(h+dy-1)*256 + (wc+dx-1)] : 0.f;
                s += wk[dy*3+dx] * v;
            }
        s = s > 0.f ? s : 0.01f * s;
        size_t oi = (size_t)c * HWSZ + hw;
        if (ADDRES) ob[oi] = s + ob[oi];
        else        ob[oi] = s;
    }
}

// ---------------------------------------------------------------------------
// ws layout (38.93 MB total):
//   wgt   f32  @0          1179648 floats ( 4.50 MB)  adaptive weights
//   bufb  f32  @1179648    8388608 floats (32.00 MB)  xa / maska
//   wb    bf16 @38273024 B  329728 elems  ( 0.63 MB)  prepped conv weights
//   bufa = out_m half of d_out (scratch until final kernel overwrites it)
// ---------------------------------------------------------------------------
extern "C" void kernel_launch(void* const* d_in, const int* in_sizes, int n_in,
                              void* d_out, int out_size, void* d_ws, size_t ws_size,
                              hipStream_t stream)
{
    const float* x     = (const float*)d_in[0];
    const float* mask  = (const float*)d_in[1];
    const float* aw1_w = (const float*)d_in[2];
    const float* aw1_b = (const float*)d_in[3];
    const float* mt1_w = (const float*)d_in[4];
    const float* mt1_b = (const float*)d_in[5];
    const float* c1_w  = (const float*)d_in[6];
    const float* c1_b  = (const float*)d_in[7];
    const float* aw2_w = (const float*)d_in[8];
    const float* aw2_b = (const float*)d_in[9];
    const float* mt2_w = (const float*)d_in[10];
    const float* mt2_b = (const float*)d_in[11];
    const float* c2_w  = (const float*)d_in[12];
    const float* c2_b  = (const float*)d_in[13];
    const float* cr_w  = (const float*)d_in[14];
    const float* cr_b  = (const float*)d_in[15];

    float* out_x = (float*)d_out;
    float* out_m = (float*)d_out + 8388608;

    float*  ws   = (float*)d_ws;
    float*  wgt  = ws;
    float*  bufb = ws + 1179648;
    float*  bufa = out_m;   // scratch until final kernel overwrites it
    __bf16* wbase = (__bf16*)((char*)d_ws + 38273024);
    __bf16* wb_c1  = wbase;            // [9][4][2][64][8]   36864
    __bf16* wb_c2  = wbase + 36864;    // [9][4][2][64][8]   36864
    __bf16* wb_mt1 = wbase + 73728;    // [25][4][2][64][8] 102400
    __bf16* wb_mt2 = wbase + 176128;   // [25][4][2][64][8] 102400
    __bf16* wb_aw1 = wbase + 278528;   // [25][1][2][64][8]  25600
    __bf16* wb_aw2 = wbase + 304128;   // [25][1][2][64][8]  25600

    dim3 blk(256);
    dim3 gconv(16, 16, 2);
    dim3 gpix(512);

    // 0. weight prep (bf16, fragment-direct layouts)
    k_prep<9, 64><<<144, blk, 0, stream>>>(c1_w,  wb_c1);
    k_prep<9, 64><<<144, blk, 0, stream>>>(c2_w,  wb_c2);
    k_prep<25,64><<<400, blk, 0, stream>>>(mt1_w, wb_mt1);
    k_prep<25,64><<<400, blk, 0, stream>>>(mt2_w, wb_mt2);
    k_prep<25, 9><<<100, blk, 0, stream>>>(aw1_w, wb_aw1);
    k_prep<25, 9><<<100, blk, 0, stream>>>(aw2_w, wb_aw2);

    // 1. res = conv1x1(x) -> out_x (consumed in-place by step 8)
    k_conv1x1<<<gpix, blk, 0, stream>>>(x, cr_w, cr_b, out_x);
    // 2. weight1 = conv5x5_9(mask, aw1) -> wgt
    k_mconv<5,1,0><<<gconv, blk, 0, stream>>>(mask, wb_aw1, aw1_b, wgt);
    // 3. x1 = conv3x3(x, c1) -> bufa
    k_mconv<3,4,0><<<gconv, blk, 0, stream>>>(x, wb_c1, c1_b, bufa);
    // 4. xa = lrelu(ada(weight1, x1)) -> bufb
    k_ada<0><<<gpix, blk, 0, stream>>>(wgt, bufa, bufb);
    // 5. x2 = conv3x3(xa, c2) -> bufa
    k_mconv<3,4,0><<<gconv, blk, 0, stream>>>(bufb, wb_c2, c2_b, bufa);
    // 6. maska = lrelu(conv5x5(mask, mt1)) -> bufb
    k_mconv<5,4,1><<<gconv, blk, 0, stream>>>(mask, wb_mt1, mt1_b, bufb);
    // 7. weight2 = conv5x5_9(maska, aw2) -> wgt
    k_mconv<5,1,0><<<gconv, blk, 0, stream>>>(bufb, wb_aw2, aw2_b, wgt);
    // 8. out_x = lrelu(ada(weight2, x2)) + res   (in-place add)
    k_ada<1><<<gpix, blk, 0, stream>>>(wgt, bufa, out_x);
    // 9. out_m = lrelu(conv5x5(maska, mt2))  (overwrites bufa scratch)
    k_mconv<5,4,1><<<gconv, blk, 0, stream>>>(bufb, wb_mt2, mt2_b, out_m);
}

// Round 5
// 432.837 us; speedup vs baseline: 1.1699x; 1.1699x over previous
//
#include <hip/hip_runtime.h>

#define HWSZ 65536   // 256*256
#define CCH  64

typedef __bf16 bf16x8 __attribute__((ext_vector_type(8)));
typedef float  f32x4  __attribute__((ext_vector_type(4)));

__device__ inline void gload_lds16(const void* g, void* l) {
    __builtin_amdgcn_global_load_lds(
        (const __attribute__((address_space(1))) void*)g,
        (__attribute__((address_space(3))) void*)l, 16, 0, 0);
}

// ---------------------------------------------------------------------------
// Weight prep: f32 src [OC][64][KK] -> bf16 dst [KK][OROWS*8 units of 16B],
// stored INVERSE-SWIZZLED so a linear global_load_lds + XOR-swizzled read
// reproduces the conflict-free layout (rule: both-sides-or-neither):
//   dst unit (o*8 + (s ^ (o&7))) holds W[o][i = s*8 .. s*8+7]   (bf16 x8)
// ---------------------------------------------------------------------------
template<int KK, int OC>
__global__ __launch_bounds__(256) void k_prep(
    const float* __restrict__ src, __bf16* __restrict__ dst)
{
    constexpr int OROWS = (OC == 9) ? 16 : 64;
    int t = blockIdx.x * 256 + threadIdx.x;
    if (t >= KK * OROWS * 64) return;
    int j  = t & 7;
    int u  = (t >> 3) % (OROWS * 8);    // 16B unit within slice
    int k  = t / (OROWS * 8 * 8);
    int o  = u >> 3;
    int s  = (u & 7) ^ (o & 7);         // inverse of read swizzle
    int i  = s * 8 + j;
    float v = (o < OC) ? src[((size_t)o * 64 + i) * KK + k] : 0.f;
    dst[t] = (__bf16)v;
}

// ---------------------------------------------------------------------------
// MFMA implicit-GEMM conv. Block = 16x16 pixel tile, 4 waves; wave computes
// M = MF*16 out-ch x 64 pixels (4 rows) via mfma_f32_16x16x32_bf16.
// x-tile staged ONCE in LDS ([pix][64ch] bf16, XOR-swizzled 16B slots).
// W slices: double-buffered LDS, async global_load_lds, 2-phase pipeline
// with RAW s_barriers + counted vmcnt (no full drains in the k-loop).
// ---------------------------------------------------------------------------
template<int KSZ, int MF, int RELU>
__global__ __launch_bounds__(256) void k_mconv(
    const float* __restrict__ x, const __bf16* __restrict__ wb,
    const float* __restrict__ bias, float* __restrict__ out)
{
    constexpr int PAD   = KSZ / 2;
    constexpr int TW    = 16 + 2 * PAD;     // 18 or 20
    constexpr int NPIX  = TW * TW;          // 324 or 400
    constexpr int KK    = KSZ * KSZ;        // 9 or 25
    constexpr int OUTC  = (MF == 1) ? 9 : 64;
    constexpr int OROWS = MF * 16;          // 16 or 64
    constexpr int SLICE = OROWS * 128;      // bytes per W slice (2048/8192)

    __shared__ __align__(16) __bf16 lx[NPIX * 64];       // swizzled 128-B rows
    __shared__ __align__(16) __bf16 lw[2][OROWS * 64];   // double-buffered W
    __shared__ float lb[64];

    const int t    = threadIdx.x;
    const int w0   = blockIdx.x * 16, h0 = blockIdx.y * 16, b = blockIdx.z;
    const int wvv  = t >> 6;
    const int lane = t & 63;
    const int px   = lane & 15;       // A-row / B-col selector
    const int g    = lane >> 4;       // k-group 0..3

    auto STAGE = [&](int k, int buf) {
        const char* gs = (const char*)wb + (size_t)k * SLICE;
        char* lbase = (char*)lw[buf];
        if constexpr (MF == 4) {
            #pragma unroll
            for (int r = 0; r < 2; ++r) {
                int u = wvv * 128 + r * 64;     // 16B-unit base for this wave
                gload_lds16(gs + (u + lane) * 16, lbase + u * 16);
            }
        } else {
            if (wvv < 2) {
                int u = wvv * 64;
                gload_lds16(gs + (u + lane) * 16, lbase + u * 16);
            }
        }
    };

    // prologue: issue W slices 0,1 (land under the x-stage)
    STAGE(0, 0);
    STAGE(1, 1);

    if (t < 64) lb[t] = (t < OUTC) ? bias[t] : 0.f;

    // ---- stage x tile: global f32 [c][gy][gx] -> LDS bf16 [pix][c] swizzled
    const float* xb = x + (size_t)b * CCH * HWSZ;
    for (int e = t; e < NPIX * 64; e += 256) {
        int c   = e / NPIX;
        int pix = e - c * NPIX;
        int sy  = pix / TW, sx = pix - sy * TW;
        int gy  = h0 + sy - PAD, gx = w0 + sx - PAD;
        float v = 0.f;
        if ((unsigned)gy < 256u && (unsigned)gx < 256u)
            v = xb[(size_t)c * HWSZ + gy * 256 + gx];
        int byteoff = (pix << 7) + (((c << 1)) ^ ((pix & 7) << 4));
        *(__bf16*)((char*)lx + byteoff) = (__bf16)v;
    }
    __syncthreads();   // full drain once: x, lb, W slices 0 & 1 all resident

    f32x4 acc[MF][4];
    #pragma unroll
    for (int m = 0; m < MF; ++m)
        #pragma unroll
        for (int nf = 0; nf < 4; ++nf)
            acc[m][nf] = (f32x4){0.f, 0.f, 0.f, 0.f};

    #pragma unroll
    for (int k = 0; k < KK; ++k) {
        const __bf16* lwb = lw[k & 1];
        const int dy = k / KSZ, dx = k - dy * KSZ;

        // ---- compute(k)
        bf16x8 bfr[4][2];
        #pragma unroll
        for (int nf = 0; nf < 4; ++nf) {
            int pix = (wvv * 4 + nf + dy) * TW + (px + dx);
            int rowbase = pix << 7, sw = (pix & 7) << 4;
            #pragma unroll
            for (int ks = 0; ks < 2; ++ks)
                bfr[nf][ks] = *(const bf16x8*)((const char*)lx + rowbase + ((((ks * 4 + g) << 4)) ^ sw));
        }
        bf16x8 afr[MF][2];
        #pragma unroll
        for (int m = 0; m < MF; ++m) {
            int o = m * 16 + px;
            int rowbase = o << 7, sw = (o & 7) << 4;
            #pragma unroll
            for (int ks = 0; ks < 2; ++ks)
                afr[m][ks] = *(const bf16x8*)((const char*)lwb + rowbase + ((((ks * 4 + g) << 4)) ^ sw));
        }
        #pragma unroll
        for (int m = 0; m < MF; ++m)
            #pragma unroll
            for (int nf = 0; nf < 4; ++nf)
                #pragma unroll
                for (int ks = 0; ks < 2; ++ks)
                    acc[m][nf] = __builtin_amdgcn_mfma_f32_16x16x32_bf16(
                        afr[m][ks], bfr[nf][ks], acc[m][nf], 0, 0, 0);

        if (k == KK - 1) break;

        // ---- pipeline: free buffer, refill async, wait slice k+1 landed
        __builtin_amdgcn_s_barrier();            // all waves done reading lw[k&1]
        bool issued = (k + 2 < KK);
        if (issued) STAGE(k + 2, k & 1);
        if constexpr (MF == 4) {
            if (issued) asm volatile("s_waitcnt vmcnt(2)" ::: "memory");
            else        asm volatile("s_waitcnt vmcnt(0)" ::: "memory");
        } else {
            if (issued && wvv < 2) asm volatile("s_waitcnt vmcnt(1)" ::: "memory");
            else                   asm volatile("s_waitcnt vmcnt(0)" ::: "memory");
        }
        __builtin_amdgcn_sched_barrier(0);
        __builtin_amdgcn_s_barrier();            // slice k+1 visible to all waves
    }

    // ---- epilogue: D row = g*4+j (+16*m), col = px
    float* ob = out + (size_t)b * OUTC * HWSZ;
    #pragma unroll
    for (int m = 0; m < MF; ++m)
        #pragma unroll
        for (int nf = 0; nf < 4; ++nf) {
            int row = h0 + wvv * 4 + nf, col = w0 + px;
            #pragma unroll
            for (int j = 0; j < 4; ++j) {
                int o = m * 16 + g * 4 + j;
                if (o < OUTC) {
                    float v = acc[m][nf][j] + lb[o];
                    if (RELU) v = v > 0.f ? v : 0.01f * v;
                    ob[(size_t)o * HWSZ + row * 256 + col] = v;
                }
            }
        }
}

// ---------------------------------------------------------------------------
// 1x1 conv (residual), f32 (memory-bound).
// ---------------------------------------------------------------------------
__global__ __launch_bounds__(256) void k_conv1x1(
    const float* __restrict__ x, const float* __restrict__ w,
    const float* __restrict__ bias, float* __restrict__ out)
{
    __shared__ __align__(16) float lwT[4096];   // [i][o]
    __shared__ float lb[64];
    int t = threadIdx.x;
    for (int s = t; s < 4096; s += 256) lwT[s] = w[(s & 63) * 64 + (s >> 6)];
    if (t < 64) lb[t] = bias[t];
    __syncthreads();

    int p  = blockIdx.x * 256 + t;
    int b  = p >> 16, hw = p & 65535;
    const float* xp = x + (size_t)b * CCH * HWSZ + hw;

    float acc[64];
    #pragma unroll
    for (int o = 0; o < 64; ++o) acc[o] = lb[o];

    #pragma unroll 4
    for (int i = 0; i < 64; ++i) {
        float xi = xp[(size_t)i * HWSZ];
        const float4* w4 = (const float4*)&lwT[i * 64];
        #pragma unroll
        for (int o4 = 0; o4 < 16; ++o4) {
            float4 wv = w4[o4];
            acc[o4*4+0] += wv.x * xi;
            acc[o4*4+1] += wv.y * xi;
            acc[o4*4+2] += wv.z * xi;
            acc[o4*4+3] += wv.w * xi;
        }
    }
    float* op = out + (size_t)b * CCH * HWSZ + hw;
    #pragma unroll
    for (int o = 0; o < 64; ++o) op[(size_t)o * HWSZ] = acc[o];
}

// ---------------------------------------------------------------------------
// Adaptive einsum (+ optional in-place residual add), f32 (memory-bound).
// ---------------------------------------------------------------------------
template<int ADDRES>
__global__ __launch_bounds__(256) void k_ada(
    const float* __restrict__ wgt, const float* __restrict__ xin,
    float* __restrict__ out)
{
    int p  = blockIdx.x * 256 + threadIdx.x;
    int b  = p >> 16, hw = p & 65535;
    int h  = hw >> 8, wc = hw & 255;

    const float* wp = wgt + (size_t)b * 9 * HWSZ + hw;
    float wk[9];
    #pragma unroll
    for (int k = 0; k < 9; ++k) wk[k] = wp[(size_t)k * HWSZ];

    bool oky[3], okx[3];
    #pragma unroll
    for (int d = 0; d < 3; ++d) {
        oky[d] = (unsigned)(h  + d - 1) < 256u;
        okx[d] = (unsigned)(wc + d - 1) < 256u;
    }

    const float* xb = xin + (size_t)b * CCH * HWSZ;
    float*       ob = out + (size_t)b * CCH * HWSZ;

    for (int c = 0; c < 64; ++c) {
        const float* xc = xb + (size_t)c * HWSZ;
        float s = 0.f;
        #pragma unroll
        for (int dy = 0; dy < 3; ++dy)
            #pragma unroll
            for (int dx = 0; dx < 3; ++dx) {
                float v = (oky[dy] && okx[dx]) ? xc[(h+dy-1)*256 + (wc+dx-1)] : 0.f;
                s += wk[dy*3+dx] * v;
            }
        s = s > 0.f ? s : 0.01f * s;
        size_t oi = (size_t)c * HWSZ + hw;
        if (ADDRES) ob[oi] = s + ob[oi];
        else        ob[oi] = s;
    }
}

// ---------------------------------------------------------------------------
// ws layout (38.93 MB total):
//   wgt   f32  @0          1179648 floats ( 4.50 MB)  adaptive weights
//   bufb  f32  @1179648    8388608 floats (32.00 MB)  xa / maska
//   wb    bf16 @38273024 B  329728 elems  ( 0.63 MB)  prepped conv weights
//   bufa = out_m half of d_out (scratch until final kernel overwrites it)
// ---------------------------------------------------------------------------
extern "C" void kernel_launch(void* const* d_in, const int* in_sizes, int n_in,
                              void* d_out, int out_size, void* d_ws, size_t ws_size,
                              hipStream_t stream)
{
    const float* x     = (const float*)d_in[0];
    const float* mask  = (const float*)d_in[1];
    const float* aw1_w = (const float*)d_in[2];
    const float* aw1_b = (const float*)d_in[3];
    const float* mt1_w = (const float*)d_in[4];
    const float* mt1_b = (const float*)d_in[5];
    const float* c1_w  = (const float*)d_in[6];
    const float* c1_b  = (const float*)d_in[7];
    const float* aw2_w = (const float*)d_in[8];
    const float* aw2_b = (const float*)d_in[9];
    const float* mt2_w = (const float*)d_in[10];
    const float* mt2_b = (const float*)d_in[11];
    const float* c2_w  = (const float*)d_in[12];
    const float* c2_b  = (const float*)d_in[13];
    const float* cr_w  = (const float*)d_in[14];
    const float* cr_b  = (const float*)d_in[15];

    float* out_x = (float*)d_out;
    float* out_m = (float*)d_out + 8388608;

    float*  ws   = (float*)d_ws;
    float*  wgt  = ws;
    float*  bufb = ws + 1179648;
    float*  bufa = out_m;   // scratch until final kernel overwrites it
    __bf16* wbase = (__bf16*)((char*)d_ws + 38273024);
    __bf16* wb_c1  = wbase;            // [9] slices of 64 rows    36864
    __bf16* wb_c2  = wbase + 36864;    //                          36864
    __bf16* wb_mt1 = wbase + 73728;    // [25] slices of 64 rows  102400
    __bf16* wb_mt2 = wbase + 176128;   //                         102400
    __bf16* wb_aw1 = wbase + 278528;   // [25] slices of 16 rows   25600
    __bf16* wb_aw2 = wbase + 304128;   //                          25600

    dim3 blk(256);
    dim3 gconv(16, 16, 2);
    dim3 gpix(512);

    // 0. weight prep (bf16, inverse-swizzled linear slices)
    k_prep<9, 64><<<144, blk, 0, stream>>>(c1_w,  wb_c1);
    k_prep<9, 64><<<144, blk, 0, stream>>>(c2_w,  wb_c2);
    k_prep<25,64><<<400, blk, 0, stream>>>(mt1_w, wb_mt1);
    k_prep<25,64><<<400, blk, 0, stream>>>(mt2_w, wb_mt2);
    k_prep<25, 9><<<100, blk, 0, stream>>>(aw1_w, wb_aw1);
    k_prep<25, 9><<<100, blk, 0, stream>>>(aw2_w, wb_aw2);

    // 1. res = conv1x1(x) -> out_x (consumed in-place by step 8)
    k_conv1x1<<<gpix, blk, 0, stream>>>(x, cr_w, cr_b, out_x);
    // 2. weight1 = conv5x5_9(mask, aw1) -> wgt
    k_mconv<5,1,0><<<gconv, blk, 0, stream>>>(mask, wb_aw1, aw1_b, wgt);
    // 3. x1 = conv3x3(x, c1) -> bufa
    k_mconv<3,4,0><<<gconv, blk, 0, stream>>>(x, wb_c1, c1_b, bufa);
    // 4. xa = lrelu(ada(weight1, x1)) -> bufb
    k_ada<0><<<gpix, blk, 0, stream>>>(wgt, bufa, bufb);
    // 5. x2 = conv3x3(xa, c2) -> bufa
    k_mconv<3,4,0><<<gconv, blk, 0, stream>>>(bufb, wb_c2, c2_b, bufa);
    // 6. maska = lrelu(conv5x5(mask, mt1)) -> bufb
    k_mconv<5,4,1><<<gconv, blk, 0, stream>>>(mask, wb_mt1, mt1_b, bufb);
    // 7. weight2 = conv5x5_9(maska, aw2) -> wgt
    k_mconv<5,1,0><<<gconv, blk, 0, stream>>>(bufb, wb_aw2, aw2_b, wgt);
    // 8. out_x = lrelu(ada(weight2, x2)) + res   (in-place add)
    k_ada<1><<<gpix, blk, 0, stream>>>(wgt, bufa, out_x);
    // 9. out_m = lrelu(conv5x5(maska, mt2))  (overwrites bufa scratch)
    k_mconv<5,4,1><<<gconv, blk, 0, stream>>>(bufb, wb_mt2, mt2_b, out_m);
}

// Round 6
// 355.714 us; speedup vs baseline: 1.4236x; 1.2168x over previous
//
#include <hip/hip_runtime.h>

#define HWSZ 65536   // 256*256
#define CCH  64

typedef __bf16 bf16x8 __attribute__((ext_vector_type(8)));
typedef float  f32x4  __attribute__((ext_vector_type(4)));

__device__ inline void gload_lds16(const void* g, void* l) {
    __builtin_amdgcn_global_load_lds(
        (const __attribute__((address_space(1))) void*)g,
        (__attribute__((address_space(3))) void*)l, 16, 0, 0);
}

// ---------------------------------------------------------------------------
// Prep for 3x3 convs: f32 [64][64][9] -> bf16 [9][64 rows][64], rows stored
// inverse-swizzled so linear global_load_lds + XOR-swizzled read is
// conflict-free (both-sides-or-neither).
// ---------------------------------------------------------------------------
__global__ __launch_bounds__(256) void k_prep3(
    const float* __restrict__ src, __bf16* __restrict__ dst)
{
    int t = blockIdx.x * 256 + threadIdx.x;
    if (t >= 9 * 64 * 64) return;
    int j = t & 7;
    int u = (t >> 3) % 512;          // 16B unit within slice
    int k = t / 4096;
    int o = u >> 3;
    int s = (u & 7) ^ (o & 7);       // inverse of read swizzle
    int i = s * 8 + j;
    dst[t] = (__bf16)src[((size_t)o * 64 + i) * 9 + k];
}

// ---------------------------------------------------------------------------
// Prep for fused 5x5: combined slices [25][96 rows][64] bf16; rows 0-63 = mt
// weights, 64-72 = aw weights, 73-95 = zero pad. Inverse-swizzled.
// ---------------------------------------------------------------------------
__global__ __launch_bounds__(256) void k_prepF(
    const float* __restrict__ mt, const float* __restrict__ aw,
    __bf16* __restrict__ dst)
{
    int t = blockIdx.x * 256 + threadIdx.x;
    if (t >= 25 * 96 * 64) return;
    int j = t & 7;
    int u = (t >> 3) % 768;
    int k = t / 6144;
    int r = u >> 3;
    int s = (u & 7) ^ (r & 7);
    int i = s * 8 + j;
    float v = 0.f;
    if (r < 64)      v = mt[((size_t)r * 64 + i) * 25 + k];
    else if (r < 73) v = aw[((size_t)(r - 64) * 64 + i) * 25 + k];
    dst[t] = (__bf16)v;
}

// ---------------------------------------------------------------------------
// MFMA implicit-GEMM conv. Block = 16x16 pixel tile, 4 waves.
// MFT=4: 64 out-ch (3x3).  MFT=5: fused — 64 mt out-ch (RELU applies) + 9 aw
// out-ch to out2 (no relu); x-stage and B-frags amortized over both.
// x-tile staged ONCE in LDS ([pix][64ch] bf16, XOR-swizzled 16B slots,
// packed ds_write_b128). W slices: double-buffered LDS, async
// global_load_lds, raw s_barriers + counted vmcnt (no in-loop full drains).
// ---------------------------------------------------------------------------
template<int KSZ, int MFT, int RELU>
__global__ __launch_bounds__(256) void k_mconv(
    const float* __restrict__ x, const __bf16* __restrict__ wb,
    const float* __restrict__ bias, const float* __restrict__ bias2,
    float* __restrict__ out, float* __restrict__ out2)
{
    constexpr int PAD   = KSZ / 2;
    constexpr int TW    = 16 + 2 * PAD;     // 18 or 20
    constexpr int NPIX  = TW * TW;          // 324 or 400
    constexpr int KK    = KSZ * KSZ;        // 9 or 25
    constexpr int SROWS = (MFT == 5) ? 96 : 64;   // staged rows (padded)
    constexpr int SLICE = SROWS * 128;            // bytes per W slice
    constexpr int NISS  = SROWS / 32;             // gload issues per lane (2/3)

    __shared__ __align__(16) __bf16 lx[NPIX * 64];        // swizzled 128-B rows
    __shared__ __align__(16) __bf16 lw[2][SROWS * 64];    // double-buffered W
    __shared__ float lb[80];

    const int t    = threadIdx.x;
    const int w0   = blockIdx.x * 16, h0 = blockIdx.y * 16, b = blockIdx.z;
    const int wvv  = t >> 6;
    const int lane = t & 63;
    const int px   = lane & 15;       // A-row / B-col selector
    const int g    = lane >> 4;       // k-group 0..3

    auto STAGE = [&](int k, int buf) {
        const char* gs = (const char*)wb + (size_t)k * SLICE;
        char* lbase = (char*)lw[buf];
        #pragma unroll
        for (int r = 0; r < NISS; ++r) {
            int ub = (wvv * NISS + r) * 64;          // uniform 16B-unit base
            gload_lds16(gs + (ub + lane) * 16, lbase + ub * 16);
        }
    };

    // prologue: issue W slices 0,1 (land under the x-stage)
    STAGE(0, 0);
    STAGE(1, 1);

    if (t < 64) lb[t] = bias[t];
    if constexpr (MFT == 5) {
        if (t >= 64 && t < 80) lb[t] = (t - 64 < 9) ? bias2[t - 64] : 0.f;
    }

    // ---- stage x tile: per-pixel address once, 64 channels packed 8-wide
    const float* xb = x + (size_t)b * CCH * HWSZ;
    constexpr int PITER = (NPIX + 255) / 256;
    #pragma unroll
    for (int pi = 0; pi < PITER; ++pi) {
        int pix = pi * 256 + t;
        if (pix < NPIX) {
            int sy = pix / TW, sx = pix - sy * TW;
            int gy = h0 + sy - PAD, gx = w0 + sx - PAD;
            bool ok = (unsigned)gy < 256u && (unsigned)gx < 256u;
            const float* src = xb + (gy * 256 + gx);
            int rowbase = pix << 7, sw = (pix & 7) << 4;
            #pragma unroll
            for (int c8 = 0; c8 < 8; ++c8) {
                bf16x8 v8;
                #pragma unroll
                for (int j = 0; j < 8; ++j) {
                    float v = ok ? src[(size_t)(c8 * 8 + j) * HWSZ] : 0.f;
                    v8[j] = (__bf16)v;
                }
                *(bf16x8*)((char*)lx + rowbase + ((c8 << 4) ^ sw)) = v8;
            }
        }
    }
    __syncthreads();   // full drain once: x, lb, W slices 0 & 1 resident

    f32x4 acc[MFT][4];
    #pragma unroll
    for (int m = 0; m < MFT; ++m)
        #pragma unroll
        for (int nf = 0; nf < 4; ++nf)
            acc[m][nf] = (f32x4){0.f, 0.f, 0.f, 0.f};

    #pragma unroll
    for (int k = 0; k < KK; ++k) {
        const __bf16* lwb = lw[k & 1];
        const int dy = k / KSZ, dx = k - dy * KSZ;

        // ---- compute(k)
        bf16x8 bfr[4][2];
        #pragma unroll
        for (int nf = 0; nf < 4; ++nf) {
            int pix = (wvv * 4 + nf + dy) * TW + (px + dx);
            int rowbase = pix << 7, sw = (pix & 7) << 4;
            #pragma unroll
            for (int ks = 0; ks < 2; ++ks)
                bfr[nf][ks] = *(const bf16x8*)((const char*)lx + rowbase + ((((ks * 4 + g) << 4)) ^ sw));
        }
        bf16x8 afr[MFT][2];
        #pragma unroll
        for (int m = 0; m < MFT; ++m) {
            int o = m * 16 + px;
            int rowbase = o << 7, sw = (o & 7) << 4;
            #pragma unroll
            for (int ks = 0; ks < 2; ++ks)
                afr[m][ks] = *(const bf16x8*)((const char*)lwb + rowbase + ((((ks * 4 + g) << 4)) ^ sw));
        }
        #pragma unroll
        for (int m = 0; m < MFT; ++m)
            #pragma unroll
            for (int nf = 0; nf < 4; ++nf)
                #pragma unroll
                for (int ks = 0; ks < 2; ++ks)
                    acc[m][nf] = __builtin_amdgcn_mfma_f32_16x16x32_bf16(
                        afr[m][ks], bfr[nf][ks], acc[m][nf], 0, 0, 0);

        if (k == KK - 1) break;

        // ---- pipeline: own ds_reads done -> barrier -> refill -> wait k+1
        asm volatile("s_waitcnt lgkmcnt(0)" ::: "memory");
        __builtin_amdgcn_sched_barrier(0);
        __builtin_amdgcn_s_barrier();            // all waves done reading lw[k&1]
        bool issued = (k + 2 < KK);
        if (issued) {
            STAGE(k + 2, k & 1);
            if constexpr (NISS == 2) asm volatile("s_waitcnt vmcnt(2)" ::: "memory");
            else                     asm volatile("s_waitcnt vmcnt(3)" ::: "memory");
        } else {
            asm volatile("s_waitcnt vmcnt(0)" ::: "memory");
        }
        __builtin_amdgcn_sched_barrier(0);
        __builtin_amdgcn_s_barrier();            // slice k+1 visible to all waves
    }

    // ---- epilogue: D row = g*4+j (+16*m), col = px
    float* ob = out + (size_t)b * 64 * HWSZ;
    #pragma unroll
    for (int m = 0; m < MFT; ++m) {
        #pragma unroll
        for (int nf = 0; nf < 4; ++nf) {
            int row = h0 + wvv * 4 + nf, col = w0 + px;
            if (m < 4) {
                #pragma unroll
                for (int j = 0; j < 4; ++j) {
                    int o = m * 16 + g * 4 + j;
                    float v = acc[m][nf][j] + lb[o];
                    if (RELU) v = v > 0.f ? v : 0.01f * v;
                    ob[(size_t)o * HWSZ + row * 256 + col] = v;
                }
            } else {
                float* ob2 = out2 + (size_t)b * 9 * HWSZ;
                #pragma unroll
                for (int j = 0; j < 4; ++j) {
                    int o2 = g * 4 + j;
                    if (o2 < 9) {
                        float v = acc[m][nf][j] + lb[64 + o2];
                        ob2[(size_t)o2 * HWSZ + row * 256 + col] = v;
                    }
                }
            }
        }
    }
}

// ---------------------------------------------------------------------------
// 1x1 conv (residual), f32 (memory-bound).
// ---------------------------------------------------------------------------
__global__ __launch_bounds__(256) void k_conv1x1(
    const float* __restrict__ x, const float* __restrict__ w,
    const float* __restrict__ bias, float* __restrict__ out)
{
    __shared__ __align__(16) float lwT[4096];   // [i][o]
    __shared__ float lb[64];
    int t = threadIdx.x;
    for (int s = t; s < 4096; s += 256) lwT[s] = w[(s & 63) * 64 + (s >> 6)];
    if (t < 64) lb[t] = bias[t];
    __syncthreads();

    int p  = blockIdx.x * 256 + t;
    int b  = p >> 16, hw = p & 65535;
    const float* xp = x + (size_t)b * CCH * HWSZ + hw;

    float acc[64];
    #pragma unroll
    for (int o = 0; o < 64; ++o) acc[o] = lb[o];

    #pragma unroll 4
    for (int i = 0; i < 64; ++i) {
        float xi = xp[(size_t)i * HWSZ];
        const float4* w4 = (const float4*)&lwT[i * 64];
        #pragma unroll
        for (int o4 = 0; o4 < 16; ++o4) {
            float4 wv = w4[o4];
            acc[o4*4+0] += wv.x * xi;
            acc[o4*4+1] += wv.y * xi;
            acc[o4*4+2] += wv.z * xi;
            acc[o4*4+3] += wv.w * xi;
        }
    }
    float* op = out + (size_t)b * CCH * HWSZ + hw;
    #pragma unroll
    for (int o = 0; o < 64; ++o) op[(size_t)o * HWSZ] = acc[o];
}

// ---------------------------------------------------------------------------
// Adaptive einsum (+ optional in-place residual add), f32 (memory-bound).
// ---------------------------------------------------------------------------
template<int ADDRES>
__global__ __launch_bounds__(256) void k_ada(
    const float* __restrict__ wgt, const float* __restrict__ xin,
    float* __restrict__ out)
{
    int p  = blockIdx.x * 256 + threadIdx.x;
    int b  = p >> 16, hw = p & 65535;
    int h  = hw >> 8, wc = hw & 255;

    const float* wp = wgt + (size_t)b * 9 * HWSZ + hw;
    float wk[9];
    #pragma unroll
    for (int k = 0; k < 9; ++k) wk[k] = wp[(size_t)k * HWSZ];

    bool oky[3], okx[3];
    #pragma unroll
    for (int d = 0; d < 3; ++d) {
        oky[d] = (unsigned)(h  + d - 1) < 256u;
        okx[d] = (unsigned)(wc + d - 1) < 256u;
    }

    const float* xb = xin + (size_t)b * CCH * HWSZ;
    float*       ob = out + (size_t)b * CCH * HWSZ;

    for (int c = 0; c < 64; ++c) {
        const float* xc = xb + (size_t)c * HWSZ;
        float s = 0.f;
        #pragma unroll
        for (int dy = 0; dy < 3; ++dy)
            #pragma unroll
            for (int dx = 0; dx < 3; ++dx) {
                float v = (oky[dy] && okx[dx]) ? xc[(h+dy-1)*256 + (wc+dx-1)] : 0.f;
                s += wk[dy*3+dx] * v;
            }
        s = s > 0.f ? s : 0.01f * s;
        size_t oi = (size_t)c * HWSZ + hw;
        if (ADDRES) ob[oi] = s + ob[oi];
        else        ob[oi] = s;
    }
}

// ---------------------------------------------------------------------------
// Buffer plan (ws = 39.0 MB):
//   wgt  f32 @0         1179648 floats ( 4.5 MB)  adaptive weights (reused:
//                        F1->ada1, F2->ada2 — sequential live ranges)
//   bufb f32 @1179648   8388608 floats (32.0 MB)  maska, then x2
//   wb   bf16 @38273024B 380928 elems  ( 0.73 MB) prepped conv weights
//   out_m scratch: x1 (dead before F2 writes final mask)
//   out_x scratch: xa (dead before conv1x1 writes res; ada2 finalizes)
// Order: F1, c3_1, ada1, F2, c3_2, conv1x1, ada2.
// ---------------------------------------------------------------------------
extern "C" void kernel_launch(void* const* d_in, const int* in_sizes, int n_in,
                              void* d_out, int out_size, void* d_ws, size_t ws_size,
                              hipStream_t stream)
{
    const float* x     = (const float*)d_in[0];
    const float* mask  = (const float*)d_in[1];
    const float* aw1_w = (const float*)d_in[2];
    const float* aw1_b = (const float*)d_in[3];
    const float* mt1_w = (const float*)d_in[4];
    const float* mt1_b = (const float*)d_in[5];
    const float* aw2_w = (const float*)d_in[8];
    const float* aw2_b = (const float*)d_in[9];
    const float* c1_w  = (const float*)d_in[6];
    const float* c1_b  = (const float*)d_in[7];
    const float* mt2_w = (const float*)d_in[10];
    const float* mt2_b = (const float*)d_in[11];
    const float* c2_w  = (const float*)d_in[12];
    const float* c2_b  = (const float*)d_in[13];
    const float* cr_w  = (const float*)d_in[14];
    const float* cr_b  = (const float*)d_in[15];

    float* out_x = (float*)d_out;
    float* out_m = (float*)d_out + 8388608;

    float*  ws   = (float*)d_ws;
    float*  wgt  = ws;
    float*  bufb = ws + 1179648;
    __bf16* wbase = (__bf16*)(ws + 1179648 + 8388608);
    __bf16* wb_c1 = wbase;             // [9][64][64]    36864
    __bf16* wb_c2 = wbase + 36864;     //                36864
    __bf16* wb_F1 = wbase + 73728;     // [25][96][64]  153600
    __bf16* wb_F2 = wbase + 227328;    //               153600

    dim3 blk(256);
    dim3 gconv(16, 16, 2);
    dim3 gpix(512);

    // 0. weight prep
    k_prep3<<<144, blk, 0, stream>>>(c1_w, wb_c1);
    k_prep3<<<144, blk, 0, stream>>>(c2_w, wb_c2);
    k_prepF<<<600, blk, 0, stream>>>(mt1_w, aw1_w, wb_F1);
    k_prepF<<<600, blk, 0, stream>>>(mt2_w, aw2_w, wb_F2);

    // 1. F1(mask): maska=lrelu(mt1) -> bufb, weight1=aw1 -> wgt
    k_mconv<5,5,1><<<gconv, blk, 0, stream>>>(mask, wb_F1, mt1_b, aw1_b, bufb, wgt);
    // 2. x1 = conv3x3(x, c1) -> out_m (scratch)
    k_mconv<3,4,0><<<gconv, blk, 0, stream>>>(x, wb_c1, c1_b, nullptr, out_m, nullptr);
    // 3. xa = lrelu(ada(wgt, x1)) -> out_x (scratch)
    k_ada<0><<<gpix, blk, 0, stream>>>(wgt, out_m, out_x);
    // 4. F2(maska): final mask=lrelu(mt2) -> out_m, weight2=aw2 -> wgt
    k_mconv<5,5,1><<<gconv, blk, 0, stream>>>(bufb, wb_F2, mt2_b, aw2_b, out_m, wgt);
    // 5. x2 = conv3x3(xa, c2) -> bufb (maska dead)
    k_mconv<3,4,0><<<gconv, blk, 0, stream>>>(out_x, wb_c2, c2_b, nullptr, bufb, nullptr);
    // 6. res = conv1x1(x) -> out_x (xa dead)
    k_conv1x1<<<gpix, blk, 0, stream>>>(x, cr_w, cr_b, out_x);
    // 7. out_x = lrelu(ada(wgt, x2)) + res
    k_ada<1><<<gpix, blk, 0, stream>>>(wgt, bufb, out_x);
}

// Round 7
// 305.819 us; speedup vs baseline: 1.6558x; 1.1632x over previous
//
#include <hip/hip_runtime.h>

#define HWSZ 65536   // 256*256
#define CCH  64

typedef __bf16 bf16x8 __attribute__((ext_vector_type(8)));
typedef __bf16 bf16x4 __attribute__((ext_vector_type(4)));
typedef float  f32x4  __attribute__((ext_vector_type(4)));

__device__ inline void gload_lds16(const void* g, void* l) {
    __builtin_amdgcn_global_load_lds(
        (const __attribute__((address_space(1))) void*)g,
        (__attribute__((address_space(3))) void*)l, 16, 0, 0);
}

// ---------------------------------------------------------------------------
// NCHW f32 -> NHWC bf16 conversion. Thread = pixel: 64 coalesced dword reads,
// 8 contiguous 16B writes.
// ---------------------------------------------------------------------------
__global__ __launch_bounds__(256) void k_cvt(
    const float* __restrict__ src, __bf16* __restrict__ dst)
{
    int p  = blockIdx.x * 256 + threadIdx.x;
    int b  = p >> 16, hw = p & 65535;
    const float* sp = src + (((size_t)b * 64) << 16) + hw;
    __bf16* dp = dst + (size_t)p * 64;
    #pragma unroll
    for (int c8 = 0; c8 < 8; ++c8) {
        bf16x8 v8;
        #pragma unroll
        for (int j = 0; j < 8; ++j)
            v8[j] = (__bf16)sp[(size_t)(c8 * 8 + j) << 16];
        *(bf16x8*)(dp + c8 * 8) = v8;
    }
}

// ---------------------------------------------------------------------------
// Prep for 3x3 convs: f32 [64][64][9] -> bf16 [9][64 rows][64], inverse-
// swizzled so linear global_load_lds + XOR-swizzled read is conflict-free.
// ---------------------------------------------------------------------------
__global__ __launch_bounds__(256) void k_prep3(
    const float* __restrict__ src, __bf16* __restrict__ dst)
{
    int t = blockIdx.x * 256 + threadIdx.x;
    if (t >= 9 * 64 * 64) return;
    int j = t & 7;
    int u = (t >> 3) % 512;
    int k = t / 4096;
    int o = u >> 3;
    int s = (u & 7) ^ (o & 7);
    int i = s * 8 + j;
    dst[t] = (__bf16)src[((size_t)o * 64 + i) * 9 + k];
}

// ---------------------------------------------------------------------------
// Prep for fused 5x5: [25][96 rows][64] bf16; rows 0-63 = mt, 64-72 = aw,
// 73-95 = zero. Inverse-swizzled.
// ---------------------------------------------------------------------------
__global__ __launch_bounds__(256) void k_prepF(
    const float* __restrict__ mt, const float* __restrict__ aw,
    __bf16* __restrict__ dst)
{
    int t = blockIdx.x * 256 + threadIdx.x;
    if (t >= 25 * 96 * 64) return;
    int j = t & 7;
    int u = (t >> 3) % 768;
    int k = t / 6144;
    int r = u >> 3;
    int s = (u & 7) ^ (r & 7);
    int i = s * 8 + j;
    float v = 0.f;
    if (r < 64)      v = mt[((size_t)r * 64 + i) * 25 + k];
    else if (r < 73) v = aw[((size_t)(r - 64) * 64 + i) * 25 + k];
    dst[t] = (__bf16)v;
}

// ---------------------------------------------------------------------------
// MFMA implicit-GEMM conv, NHWC bf16 input. Block = 16x16 pixel tile, 4
// waves. MFT=4: 64 out-ch. MFT=5: fused 64 mt + 9 aw (aw -> out2, f32 NCHW).
// EPI=0: main out as bf16 NHWC (outh); EPI=1: f32 NCHW (outf).
// x-tile staged once (8 b128 loads + 8 swizzled ds_write_b128 per pixel).
// W slices double-buffered via async global_load_lds, raw barriers +
// counted vmcnt.
// ---------------------------------------------------------------------------
template<int KSZ, int MFT, int RELU, int EPI>
__global__ __launch_bounds__(256) void k_mconv(
    const __bf16* __restrict__ xh, const __bf16* __restrict__ wb,
    const float* __restrict__ bias, const float* __restrict__ bias2,
    float* __restrict__ outf, __bf16* __restrict__ outh,
    float* __restrict__ out2)
{
    constexpr int PAD   = KSZ / 2;
    constexpr int TW    = 16 + 2 * PAD;
    constexpr int NPIX  = TW * TW;
    constexpr int KK    = KSZ * KSZ;
    constexpr int SROWS = (MFT == 5) ? 96 : 64;
    constexpr int SLICE = SROWS * 128;
    constexpr int NISS  = SROWS / 32;

    __shared__ __align__(16) __bf16 lx[NPIX * 64];
    __shared__ __align__(16) __bf16 lw[2][SROWS * 64];
    __shared__ float lb[80];

    const int t    = threadIdx.x;
    const int w0   = blockIdx.x * 16, h0 = blockIdx.y * 16, b = blockIdx.z;
    const int wvv  = t >> 6;
    const int lane = t & 63;
    const int px   = lane & 15;
    const int g    = lane >> 4;

    auto STAGE = [&](int k, int buf) {
        const char* gs = (const char*)wb + (size_t)k * SLICE;
        char* lbase = (char*)lw[buf];
        #pragma unroll
        for (int r = 0; r < NISS; ++r) {
            int ub = (wvv * NISS + r) * 64;
            gload_lds16(gs + (ub + lane) * 16, lbase + ub * 16);
        }
    };

    STAGE(0, 0);
    STAGE(1, 1);

    if (t < 64) lb[t] = bias[t];
    if constexpr (MFT == 5) {
        if (t >= 64 && t < 80) lb[t] = (t - 64 < 9) ? bias2[t - 64] : 0.f;
    }

    // ---- stage x tile from NHWC bf16
    bf16x8 zv;
    #pragma unroll
    for (int j = 0; j < 8; ++j) zv[j] = (__bf16)0.f;
    constexpr int PITER = (NPIX + 255) / 256;
    #pragma unroll
    for (int pi = 0; pi < PITER; ++pi) {
        int pix = pi * 256 + t;
        if (pix < NPIX) {
            int sy = pix / TW, sx = pix - sy * TW;
            int gy = h0 + sy - PAD, gx = w0 + sx - PAD;
            bool ok = (unsigned)gy < 256u && (unsigned)gx < 256u;
            const __bf16* src = xh + ((((size_t)b << 16) + gy * 256 + gx) << 6);
            int rowbase = pix << 7, sw = (pix & 7) << 4;
            #pragma unroll
            for (int c8 = 0; c8 < 8; ++c8) {
                bf16x8 v8 = ok ? *(const bf16x8*)(src + c8 * 8) : zv;
                *(bf16x8*)((char*)lx + rowbase + ((c8 << 4) ^ sw)) = v8;
            }
        }
    }
    __syncthreads();   // full drain once: x, lb, W slices 0 & 1 resident

    f32x4 acc[MFT][4];
    #pragma unroll
    for (int m = 0; m < MFT; ++m)
        #pragma unroll
        for (int nf = 0; nf < 4; ++nf)
            acc[m][nf] = (f32x4){0.f, 0.f, 0.f, 0.f};

    #pragma unroll
    for (int k = 0; k < KK; ++k) {
        const __bf16* lwb = lw[k & 1];
        const int dy = k / KSZ, dx = k - dy * KSZ;

        bf16x8 bfr[4][2];
        #pragma unroll
        for (int nf = 0; nf < 4; ++nf) {
            int pix = (wvv * 4 + nf + dy) * TW + (px + dx);
            int rowbase = pix << 7, sw = (pix & 7) << 4;
            #pragma unroll
            for (int ks = 0; ks < 2; ++ks)
                bfr[nf][ks] = *(const bf16x8*)((const char*)lx + rowbase + ((((ks * 4 + g) << 4)) ^ sw));
        }
        bf16x8 afr[MFT][2];
        #pragma unroll
        for (int m = 0; m < MFT; ++m) {
            int o = m * 16 + px;
            int rowbase = o << 7, sw = (o & 7) << 4;
            #pragma unroll
            for (int ks = 0; ks < 2; ++ks)
                afr[m][ks] = *(const bf16x8*)((const char*)lwb + rowbase + ((((ks * 4 + g) << 4)) ^ sw));
        }
        #pragma unroll
        for (int m = 0; m < MFT; ++m)
            #pragma unroll
            for (int nf = 0; nf < 4; ++nf)
                #pragma unroll
                for (int ks = 0; ks < 2; ++ks)
                    acc[m][nf] = __builtin_amdgcn_mfma_f32_16x16x32_bf16(
                        afr[m][ks], bfr[nf][ks], acc[m][nf], 0, 0, 0);

        if (k == KK - 1) break;

        asm volatile("s_waitcnt lgkmcnt(0)" ::: "memory");
        __builtin_amdgcn_sched_barrier(0);
        __builtin_amdgcn_s_barrier();            // all waves done with lw[k&1]
        bool issued = (k + 2 < KK);
        if (issued) {
            STAGE(k + 2, k & 1);
            if constexpr (NISS == 2) asm volatile("s_waitcnt vmcnt(2)" ::: "memory");
            else                     asm volatile("s_waitcnt vmcnt(3)" ::: "memory");
        } else {
            asm volatile("s_waitcnt vmcnt(0)" ::: "memory");
        }
        __builtin_amdgcn_sched_barrier(0);
        __builtin_amdgcn_s_barrier();            // slice k+1 visible
    }

    // ---- epilogue
    #pragma unroll
    for (int m = 0; m < MFT; ++m) {
        #pragma unroll
        for (int nf = 0; nf < 4; ++nf) {
            int row = h0 + wvv * 4 + nf, col = w0 + px;
            if (m < 4) {
                float vj[4];
                #pragma unroll
                for (int j = 0; j < 4; ++j) {
                    float v = acc[m][nf][j] + lb[m * 16 + g * 4 + j];
                    if (RELU) v = v > 0.f ? v : 0.01f * v;
                    vj[j] = v;
                }
                if constexpr (EPI == 0) {
                    bf16x4 pk;
                    #pragma unroll
                    for (int j = 0; j < 4; ++j) pk[j] = (__bf16)vj[j];
                    *(bf16x4*)(outh + ((((size_t)b << 16) + row * 256 + col) << 6)
                                    + m * 16 + g * 4) = pk;
                } else {
                    #pragma unroll
                    for (int j = 0; j < 4; ++j)
                        outf[((size_t)(b * 64 + m * 16 + g * 4 + j) << 16)
                             + row * 256 + col] = vj[j];
                }
            } else {
                #pragma unroll
                for (int j = 0; j < 4; ++j) {
                    int o2 = g * 4 + j;
                    if (o2 < 9)
                        out2[((size_t)(b * 9 + o2) << 16) + row * 256 + col]
                            = acc[m][nf][j] + lb[64 + o2];
                }
            }
        }
    }
}

// ---------------------------------------------------------------------------
// 1x1 conv (residual) from NHWC bf16 x. Thread = pixel, 64 f32 acc,
// weights [i][o] in LDS (broadcast float4 reads). Writes f32 NCHW.
// ---------------------------------------------------------------------------
__global__ __launch_bounds__(256) void k_conv1x1(
    const __bf16* __restrict__ xh, const float* __restrict__ w,
    const float* __restrict__ bias, float* __restrict__ out)
{
    __shared__ __align__(16) float lwT[4096];   // [i][o]
    __shared__ float lb[64];
    int t = threadIdx.x;
    for (int s = t; s < 4096; s += 256) lwT[s] = w[(s & 63) * 64 + (s >> 6)];
    if (t < 64) lb[t] = bias[t];
    __syncthreads();

    int p  = blockIdx.x * 256 + t;
    int b  = p >> 16, hw = p & 65535;
    const __bf16* xp = xh + (size_t)p * 64;

    float acc[64];
    #pragma unroll
    for (int o = 0; o < 64; ++o) acc[o] = lb[o];

    #pragma unroll
    for (int c8 = 0; c8 < 8; ++c8) {
        bf16x8 v8 = *(const bf16x8*)(xp + c8 * 8);
        #pragma unroll
        for (int j = 0; j < 8; ++j) {
            float xi = (float)v8[j];
            const float4* w4 = (const float4*)&lwT[(c8 * 8 + j) * 64];
            #pragma unroll
            for (int o4 = 0; o4 < 16; ++o4) {
                float4 wv = w4[o4];
                acc[o4*4+0] += wv.x * xi;
                acc[o4*4+1] += wv.y * xi;
                acc[o4*4+2] += wv.z * xi;
                acc[o4*4+3] += wv.w * xi;
            }
        }
    }
    float* op = out + (((size_t)b * 64) << 16) + hw;
    #pragma unroll
    for (int o = 0; o < 64; ++o) op[(size_t)o << 16] = acc[o];
}

// ---------------------------------------------------------------------------
// Adaptive einsum, NHWC bf16 input. MODE 0: lrelu -> bf16 NHWC out.
// MODE 1: lrelu -> += residual, f32 NCHW out.
// ---------------------------------------------------------------------------
template<int MODE>
__global__ __launch_bounds__(256) void k_ada(
    const float* __restrict__ wgt, const __bf16* __restrict__ xin,
    float* __restrict__ outf, __bf16* __restrict__ outh)
{
    int p  = blockIdx.x * 256 + threadIdx.x;
    int b  = p >> 16, hw = p & 65535;
    int h  = hw >> 8, wc = hw & 255;

    const float* wp = wgt + ((size_t)(b * 9) << 16) + hw;
    const __bf16* cen = xin + (size_t)p * 64;

    float wk[9];
    const __bf16* nbp[9];
    #pragma unroll
    for (int dy = 0; dy < 3; ++dy)
        #pragma unroll
        for (int dx = 0; dx < 3; ++dx) {
            int k = dy * 3 + dx;
            bool ok = ((unsigned)(h + dy - 1) < 256u) &&
                      ((unsigned)(wc + dx - 1) < 256u);
            wk[k]  = ok ? wp[(size_t)k << 16] : 0.f;
            nbp[k] = ok ? cen + ((dy - 1) * 256 + (dx - 1)) * 64 : cen;
        }

    #pragma unroll
    for (int c8 = 0; c8 < 8; ++c8) {
        float a[8] = {0.f,0.f,0.f,0.f,0.f,0.f,0.f,0.f};
        #pragma unroll
        for (int k = 0; k < 9; ++k) {
            bf16x8 v8 = *(const bf16x8*)(nbp[k] + c8 * 8);
            #pragma unroll
            for (int j = 0; j < 8; ++j) a[j] += wk[k] * (float)v8[j];
        }
        #pragma unroll
        for (int j = 0; j < 8; ++j) a[j] = a[j] > 0.f ? a[j] : 0.01f * a[j];
        if constexpr (MODE == 0) {
            bf16x8 o8;
            #pragma unroll
            for (int j = 0; j < 8; ++j) o8[j] = (__bf16)a[j];
            *(bf16x8*)(outh + (size_t)p * 64 + c8 * 8) = o8;
        } else {
            #pragma unroll
            for (int j = 0; j < 8; ++j) {
                size_t oi = ((size_t)(b * 64 + c8 * 8 + j) << 16) + hw;
                outf[oi] = a[j] + outf[oi];
            }
        }
    }
}

// ---------------------------------------------------------------------------
// Buffer plan (ws = 39,034,880 B — same proven footprint as round 5):
//   wgt  f32  @0           4,718,592 B   adaptive weights (F1->ada1, F2->ada2)
//   xh   bf16 @4,718,592  16,777,216 B   x in NHWC bf16 (live whole call)
//   mh / x2h  @21,495,808 16,777,216 B   mask NHWC (dead after F1), then x2
//   wb   bf16 @38,273,024    761,856 B   prepped conv weights
// d_out scratch:
//   out_x lower half = maska_h (bf16, dead when F2 runs)   [F2 writes out_m]
//   out_x upper half = xa_h    (bf16, dead after c3_2)
//   out_m lower half = x1_h    (bf16, dead before F2 writes final mask)
// Order: cvt x, cvt mask, preps, F1, c3_1, ada1, F2, c3_2, conv1x1, ada2.
// ---------------------------------------------------------------------------
extern "C" void kernel_launch(void* const* d_in, const int* in_sizes, int n_in,
                              void* d_out, int out_size, void* d_ws, size_t ws_size,
                              hipStream_t stream)
{
    const float* x     = (const float*)d_in[0];
    const float* mask  = (const float*)d_in[1];
    const float* aw1_w = (const float*)d_in[2];
    const float* aw1_b = (const float*)d_in[3];
    const float* mt1_w = (const float*)d_in[4];
    const float* mt1_b = (const float*)d_in[5];
    const float* c1_w  = (const float*)d_in[6];
    const float* c1_b  = (const float*)d_in[7];
    const float* aw2_w = (const float*)d_in[8];
    const float* aw2_b = (const float*)d_in[9];
    const float* mt2_w = (const float*)d_in[10];
    const float* mt2_b = (const float*)d_in[11];
    const float* c2_w  = (const float*)d_in[12];
    const float* c2_b  = (const float*)d_in[13];
    const float* cr_w  = (const float*)d_in[14];
    const float* cr_b  = (const float*)d_in[15];

    float* out_x = (float*)d_out;
    float* out_m = (float*)d_out + 8388608;

    float*  wgt  = (float*)d_ws;
    __bf16* xh   = (__bf16*)((char*)d_ws + 4718592);
    __bf16* mh   = (__bf16*)((char*)d_ws + 21495808);
    __bf16* x2h  = mh;                              // sequential live ranges
    __bf16* wbase = (__bf16*)((char*)d_ws + 38273024);
    __bf16* wb_c1 = wbase;             // [9][64][64]    36864
    __bf16* wb_c2 = wbase + 36864;     //                36864
    __bf16* wb_F1 = wbase + 73728;     // [25][96][64]  153600
    __bf16* wb_F2 = wbase + 227328;    //               153600

    __bf16* maska_h = (__bf16*)out_x;               // lower 16.78 MB
    __bf16* xa_h    = (__bf16*)out_x + 8388608;     // upper 16.78 MB
    __bf16* x1_h    = (__bf16*)out_m;               // lower 16.78 MB

    dim3 blk(256);
    dim3 gconv(16, 16, 2);
    dim3 gpix(512);

    // 0. layout conversion + weight prep
    k_cvt<<<gpix, blk, 0, stream>>>(x,    xh);
    k_cvt<<<gpix, blk, 0, stream>>>(mask, mh);
    k_prep3<<<144, blk, 0, stream>>>(c1_w, wb_c1);
    k_prep3<<<144, blk, 0, stream>>>(c2_w, wb_c2);
    k_prepF<<<600, blk, 0, stream>>>(mt1_w, aw1_w, wb_F1);
    k_prepF<<<600, blk, 0, stream>>>(mt2_w, aw2_w, wb_F2);

    // 1. F1(mh): maska = lrelu(mt1) -> maska_h (bf16), weight1 = aw1 -> wgt
    k_mconv<5,5,1,0><<<gconv, blk, 0, stream>>>(mh, wb_F1, mt1_b, aw1_b,
                                                nullptr, maska_h, wgt);
    // 2. x1 = conv3x3(xh, c1) -> x1_h (bf16, out_m scratch)
    k_mconv<3,4,0,0><<<gconv, blk, 0, stream>>>(xh, wb_c1, c1_b, nullptr,
                                                nullptr, x1_h, nullptr);
    // 3. xa = lrelu(ada(wgt, x1)) -> xa_h (bf16, out_x upper scratch)
    k_ada<0><<<gpix, blk, 0, stream>>>(wgt, x1_h, nullptr, xa_h);
    // 4. F2(maska_h): final mask = lrelu(mt2) -> out_m (f32), weight2 -> wgt
    k_mconv<5,5,1,1><<<gconv, blk, 0, stream>>>(maska_h, wb_F2, mt2_b, aw2_b,
                                                out_m, nullptr, wgt);
    // 5. x2 = conv3x3(xa_h, c2) -> x2h (bf16, ws)
    k_mconv<3,4,0,0><<<gconv, blk, 0, stream>>>(xa_h, wb_c2, c2_b, nullptr,
                                                nullptr, x2h, nullptr);
    // 6. res = conv1x1(xh) -> out_x (f32, clobbers dead scratch)
    k_conv1x1<<<gpix, blk, 0, stream>>>(xh, cr_w, cr_b, out_x);
    // 7. out_x = lrelu(ada(wgt, x2)) + res
    k_ada<1><<<gpix, blk, 0, stream>>>(wgt, x2h, out_x, nullptr);
}

// Round 8
// 262.833 us; speedup vs baseline: 1.9266x; 1.1635x over previous
//
#include <hip/hip_runtime.h>

#define HWSZ 65536   // 256*256
#define CCH  64

typedef __bf16 bf16x8 __attribute__((ext_vector_type(8)));
typedef __bf16 bf16x4 __attribute__((ext_vector_type(4)));
typedef float  f32x4  __attribute__((ext_vector_type(4)));

__device__ inline void gload_lds16(const void* g, void* l) {
    __builtin_amdgcn_global_load_lds(
        (const __attribute__((address_space(1))) void*)g,
        (__attribute__((address_space(3))) void*)l, 16, 0, 0);
}

// ---------------------------------------------------------------------------
// NCHW f32 -> NHWC bf16 conversion.
// ---------------------------------------------------------------------------
__global__ __launch_bounds__(256) void k_cvt(
    const float* __restrict__ src, __bf16* __restrict__ dst)
{
    int p  = blockIdx.x * 256 + threadIdx.x;
    int b  = p >> 16, hw = p & 65535;
    const float* sp = src + (((size_t)b * 64) << 16) + hw;
    __bf16* dp = dst + (size_t)p * 64;
    #pragma unroll
    for (int c8 = 0; c8 < 8; ++c8) {
        bf16x8 v8;
        #pragma unroll
        for (int j = 0; j < 8; ++j)
            v8[j] = (__bf16)sp[(size_t)(c8 * 8 + j) << 16];
        *(bf16x8*)(dp + c8 * 8) = v8;
    }
}

// ---------------------------------------------------------------------------
// Prep for 3x3 convs: f32 [64][64][9] -> bf16 [9][64 rows][64], inverse-
// swizzled so linear global_load_lds + XOR-swizzled read is conflict-free.
// ---------------------------------------------------------------------------
__global__ __launch_bounds__(256) void k_prep3(
    const float* __restrict__ src, __bf16* __restrict__ dst)
{
    int t = blockIdx.x * 256 + threadIdx.x;
    if (t >= 9 * 64 * 64) return;
    int j = t & 7;
    int u = (t >> 3) % 512;
    int k = t / 4096;
    int o = u >> 3;
    int s = (u & 7) ^ (o & 7);
    int i = s * 8 + j;
    dst[t] = (__bf16)src[((size_t)o * 64 + i) * 9 + k];
}

// ---------------------------------------------------------------------------
// Prep for fused 5x5: [25][96 rows][64] bf16; rows 0-63 = mt, 64-72 = aw,
// 73-95 = zero. Inverse-swizzled.
// ---------------------------------------------------------------------------
__global__ __launch_bounds__(256) void k_prepF(
    const float* __restrict__ mt, const float* __restrict__ aw,
    __bf16* __restrict__ dst)
{
    int t = blockIdx.x * 256 + threadIdx.x;
    if (t >= 25 * 96 * 64) return;
    int j = t & 7;
    int u = (t >> 3) % 768;
    int k = t / 6144;
    int r = u >> 3;
    int s = (u & 7) ^ (r & 7);
    int i = s * 8 + j;
    float v = 0.f;
    if (r < 64)      v = mt[((size_t)r * 64 + i) * 25 + k];
    else if (r < 73) v = aw[((size_t)(r - 64) * 64 + i) * 25 + k];
    dst[t] = (__bf16)v;
}

// ---------------------------------------------------------------------------
// MFMA implicit-GEMM conv, NHWC bf16 input. Block = 16x16 pixel tile, 4
// waves. MFT=4: 64 out-ch. MFT=5: fused 64 mt + 9 aw (aw -> out2, f32 NCHW).
// EPI=0: main out as bf16 NHWC; EPI=1: f32 NCHW.
// ---------------------------------------------------------------------------
template<int KSZ, int MFT, int RELU, int EPI>
__global__ __launch_bounds__(256) void k_mconv(
    const __bf16* __restrict__ xh, const __bf16* __restrict__ wb,
    const float* __restrict__ bias, const float* __restrict__ bias2,
    float* __restrict__ outf, __bf16* __restrict__ outh,
    float* __restrict__ out2)
{
    constexpr int PAD   = KSZ / 2;
    constexpr int TW    = 16 + 2 * PAD;
    constexpr int NPIX  = TW * TW;
    constexpr int KK    = KSZ * KSZ;
    constexpr int SROWS = (MFT == 5) ? 96 : 64;
    constexpr int SLICE = SROWS * 128;
    constexpr int NISS  = SROWS / 32;

    __shared__ __align__(16) __bf16 lx[NPIX * 64];
    __shared__ __align__(16) __bf16 lw[2][SROWS * 64];
    __shared__ float lb[80];

    const int t    = threadIdx.x;
    const int w0   = blockIdx.x * 16, h0 = blockIdx.y * 16, b = blockIdx.z;
    const int wvv  = t >> 6;
    const int lane = t & 63;
    const int px   = lane & 15;
    const int g    = lane >> 4;

    auto STAGE = [&](int k, int buf) {
        const char* gs = (const char*)wb + (size_t)k * SLICE;
        char* lbase = (char*)lw[buf];
        #pragma unroll
        for (int r = 0; r < NISS; ++r) {
            int ub = (wvv * NISS + r) * 64;
            gload_lds16(gs + (ub + lane) * 16, lbase + ub * 16);
        }
    };

    STAGE(0, 0);
    STAGE(1, 1);

    if (t < 64) lb[t] = bias[t];
    if constexpr (MFT == 5) {
        if (t >= 64 && t < 80) lb[t] = (t - 64 < 9) ? bias2[t - 64] : 0.f;
    }

    // ---- stage x tile from NHWC bf16
    bf16x8 zv;
    #pragma unroll
    for (int j = 0; j < 8; ++j) zv[j] = (__bf16)0.f;
    constexpr int PITER = (NPIX + 255) / 256;
    #pragma unroll
    for (int pi = 0; pi < PITER; ++pi) {
        int pix = pi * 256 + t;
        if (pix < NPIX) {
            int sy = pix / TW, sx = pix - sy * TW;
            int gy = h0 + sy - PAD, gx = w0 + sx - PAD;
            bool ok = (unsigned)gy < 256u && (unsigned)gx < 256u;
            const __bf16* src = xh + ((((size_t)b << 16) + gy * 256 + gx) << 6);
            int rowbase = pix << 7, sw = (pix & 7) << 4;
            #pragma unroll
            for (int c8 = 0; c8 < 8; ++c8) {
                bf16x8 v8 = ok ? *(const bf16x8*)(src + c8 * 8) : zv;
                *(bf16x8*)((char*)lx + rowbase + ((c8 << 4) ^ sw)) = v8;
            }
        }
    }
    __syncthreads();   // full drain once: x, lb, W slices 0 & 1 resident

    f32x4 acc[MFT][4];
    #pragma unroll
    for (int m = 0; m < MFT; ++m)
        #pragma unroll
        for (int nf = 0; nf < 4; ++nf)
            acc[m][nf] = (f32x4){0.f, 0.f, 0.f, 0.f};

    #pragma unroll
    for (int k = 0; k < KK; ++k) {
        const __bf16* lwb = lw[k & 1];
        const int dy = k / KSZ, dx = k - dy * KSZ;

        bf16x8 bfr[4][2];
        #pragma unroll
        for (int nf = 0; nf < 4; ++nf) {
            int pix = (wvv * 4 + nf + dy) * TW + (px + dx);
            int rowbase = pix << 7, sw = (pix & 7) << 4;
            #pragma unroll
            for (int ks = 0; ks < 2; ++ks)
                bfr[nf][ks] = *(const bf16x8*)((const char*)lx + rowbase + ((((ks * 4 + g) << 4)) ^ sw));
        }
        bf16x8 afr[MFT][2];
        #pragma unroll
        for (int m = 0; m < MFT; ++m) {
            int o = m * 16 + px;
            int rowbase = o << 7, sw = (o & 7) << 4;
            #pragma unroll
            for (int ks = 0; ks < 2; ++ks)
                afr[m][ks] = *(const bf16x8*)((const char*)lwb + rowbase + ((((ks * 4 + g) << 4)) ^ sw));
        }
        #pragma unroll
        for (int m = 0; m < MFT; ++m)
            #pragma unroll
            for (int nf = 0; nf < 4; ++nf)
                #pragma unroll
                for (int ks = 0; ks < 2; ++ks)
                    acc[m][nf] = __builtin_amdgcn_mfma_f32_16x16x32_bf16(
                        afr[m][ks], bfr[nf][ks], acc[m][nf], 0, 0, 0);

        if (k == KK - 1) break;

        asm volatile("s_waitcnt lgkmcnt(0)" ::: "memory");
        __builtin_amdgcn_sched_barrier(0);
        __builtin_amdgcn_s_barrier();            // all waves done with lw[k&1]
        bool issued = (k + 2 < KK);
        if (issued) {
            STAGE(k + 2, k & 1);
            if constexpr (NISS == 2) asm volatile("s_waitcnt vmcnt(2)" ::: "memory");
            else                     asm volatile("s_waitcnt vmcnt(3)" ::: "memory");
        } else {
            asm volatile("s_waitcnt vmcnt(0)" ::: "memory");
        }
        __builtin_amdgcn_sched_barrier(0);
        __builtin_amdgcn_s_barrier();            // slice k+1 visible
    }

    // ---- epilogue
    #pragma unroll
    for (int m = 0; m < MFT; ++m) {
        #pragma unroll
        for (int nf = 0; nf < 4; ++nf) {
            int row = h0 + wvv * 4 + nf, col = w0 + px;
            if (m < 4) {
                float vj[4];
                #pragma unroll
                for (int j = 0; j < 4; ++j) {
                    float v = acc[m][nf][j] + lb[m * 16 + g * 4 + j];
                    if (RELU) v = v > 0.f ? v : 0.01f * v;
                    vj[j] = v;
                }
                if constexpr (EPI == 0) {
                    bf16x4 pk;
                    #pragma unroll
                    for (int j = 0; j < 4; ++j) pk[j] = (__bf16)vj[j];
                    *(bf16x4*)(outh + ((((size_t)b << 16) + row * 256 + col) << 6)
                                    + m * 16 + g * 4) = pk;
                } else {
                    #pragma unroll
                    for (int j = 0; j < 4; ++j)
                        outf[((size_t)(b * 64 + m * 16 + g * 4 + j) << 16)
                             + row * 256 + col] = vj[j];
                }
            } else {
                #pragma unroll
                for (int j = 0; j < 4; ++j) {
                    int o2 = g * 4 + j;
                    if (o2 < 9)
                        out2[((size_t)(b * 9 + o2) << 16) + row * 256 + col]
                            = acc[m][nf][j] + lb[64 + o2];
                }
            }
        }
    }
}

// ---------------------------------------------------------------------------
// 1x1 conv (residual) from NHWC bf16 x. Writes f32 NCHW.
// ---------------------------------------------------------------------------
__global__ __launch_bounds__(256) void k_conv1x1(
    const __bf16* __restrict__ xh, const float* __restrict__ w,
    const float* __restrict__ bias, float* __restrict__ out)
{
    __shared__ __align__(16) float lwT[4096];   // [i][o]
    __shared__ float lb[64];
    int t = threadIdx.x;
    for (int s = t; s < 4096; s += 256) lwT[s] = w[(s & 63) * 64 + (s >> 6)];
    if (t < 64) lb[t] = bias[t];
    __syncthreads();

    int p  = blockIdx.x * 256 + t;
    int b  = p >> 16, hw = p & 65535;
    const __bf16* xp = xh + (size_t)p * 64;

    float acc[64];
    #pragma unroll
    for (int o = 0; o < 64; ++o) acc[o] = lb[o];

    #pragma unroll
    for (int c8 = 0; c8 < 8; ++c8) {
        bf16x8 v8 = *(const bf16x8*)(xp + c8 * 8);
        #pragma unroll
        for (int j = 0; j < 8; ++j) {
            float xi = (float)v8[j];
            const float4* w4 = (const float4*)&lwT[(c8 * 8 + j) * 64];
            #pragma unroll
            for (int o4 = 0; o4 < 16; ++o4) {
                float4 wv = w4[o4];
                acc[o4*4+0] += wv.x * xi;
                acc[o4*4+1] += wv.y * xi;
                acc[o4*4+2] += wv.z * xi;
                acc[o4*4+3] += wv.w * xi;
            }
        }
    }
    float* op = out + (((size_t)b * 64) << 16) + hw;
    #pragma unroll
    for (int o = 0; o < 64; ++o) op[(size_t)o << 16] = acc[o];
}

// ---------------------------------------------------------------------------
// Adaptive einsum, NHWC bf16 input. MODE 0: lrelu -> bf16 NHWC out.
// MODE 1: lrelu -> += residual, f32 NCHW out.
// k-OUTER loop: each neighbor row's full 128B consumed via 8 consecutive
// b128 loads (L1-resident) before moving to the next row — fixes the 12x
// over-fetch of the c8-outer order. XCD-contiguous row swizzle (bijective,
// 512 %% 8 == 0) keeps h±1 halo re-reads in the local XCD L2.
// ---------------------------------------------------------------------------
template<int MODE>
__global__ __launch_bounds__(256) void k_ada(
    const float* __restrict__ wgt, const __bf16* __restrict__ xin,
    float* __restrict__ outf, __bf16* __restrict__ outh)
{
    int bid = blockIdx.x;
    int sb  = (bid & 7) * 64 + (bid >> 3);      // XCD-contiguous rows
    int p   = sb * 256 + threadIdx.x;
    int b  = p >> 16, hw = p & 65535;
    int h  = hw >> 8, wc = hw & 255;

    const float* wp = wgt + ((size_t)(b * 9) << 16) + hw;
    const __bf16* cen = xin + (size_t)p * 64;

    float wk[9];
    const __bf16* nbp[9];
    #pragma unroll
    for (int dy = 0; dy < 3; ++dy)
        #pragma unroll
        for (int dx = 0; dx < 3; ++dx) {
            int k = dy * 3 + dx;
            bool ok = ((unsigned)(h + dy - 1) < 256u) &&
                      ((unsigned)(wc + dx - 1) < 256u);
            wk[k]  = ok ? wp[(size_t)k << 16] : 0.f;
            nbp[k] = ok ? cen + ((dy - 1) * 256 + (dx - 1)) * 64 : cen;
        }

    float acc[64];
    #pragma unroll
    for (int j = 0; j < 64; ++j) acc[j] = 0.f;

    #pragma unroll
    for (int k = 0; k < 9; ++k) {
        const __bf16* rp = nbp[k];
        float w = wk[k];
        #pragma unroll
        for (int c8 = 0; c8 < 8; ++c8) {
            bf16x8 v8 = *(const bf16x8*)(rp + c8 * 8);
            #pragma unroll
            for (int j = 0; j < 8; ++j)
                acc[c8 * 8 + j] += w * (float)v8[j];
        }
    }

    if constexpr (MODE == 0) {
        __bf16* op = outh + (size_t)p * 64;
        #pragma unroll
        for (int c8 = 0; c8 < 8; ++c8) {
            bf16x8 o8;
            #pragma unroll
            for (int j = 0; j < 8; ++j) {
                float v = acc[c8 * 8 + j];
                o8[j] = (__bf16)(v > 0.f ? v : 0.01f * v);
            }
            *(bf16x8*)(op + c8 * 8) = o8;
        }
    } else {
        float* op = outf + (((size_t)b * 64) << 16) + hw;
        #pragma unroll
        for (int c = 0; c < 64; ++c) {
            float v = acc[c];
            v = v > 0.f ? v : 0.01f * v;
            size_t oi = (size_t)c << 16;
            op[oi] = v + op[oi];
        }
    }
}

// ---------------------------------------------------------------------------
// Buffer plan (ws = 39,034,880 B):
//   wgt  f32  @0           4,718,592 B   adaptive weights (F1->ada1, F2->ada2)
//   xh   bf16 @4,718,592  16,777,216 B   x in NHWC bf16 (live whole call)
//   mh / x2h  @21,495,808 16,777,216 B   mask NHWC (dead after F1), then x2
//   wb   bf16 @38,273,024    761,856 B   prepped conv weights
// d_out scratch: out_x lower = maska_h, out_x upper = xa_h, out_m = x1_h.
// ---------------------------------------------------------------------------
extern "C" void kernel_launch(void* const* d_in, const int* in_sizes, int n_in,
                              void* d_out, int out_size, void* d_ws, size_t ws_size,
                              hipStream_t stream)
{
    const float* x     = (const float*)d_in[0];
    const float* mask  = (const float*)d_in[1];
    const float* aw1_w = (const float*)d_in[2];
    const float* aw1_b = (const float*)d_in[3];
    const float* mt1_w = (const float*)d_in[4];
    const float* mt1_b = (const float*)d_in[5];
    const float* c1_w  = (const float*)d_in[6];
    const float* c1_b  = (const float*)d_in[7];
    const float* aw2_w = (const float*)d_in[8];
    const float* aw2_b = (const float*)d_in[9];
    const float* mt2_w = (const float*)d_in[10];
    const float* mt2_b = (const float*)d_in[11];
    const float* c2_w  = (const float*)d_in[12];
    const float* c2_b  = (const float*)d_in[13];
    const float* cr_w  = (const float*)d_in[14];
    const float* cr_b  = (const float*)d_in[15];

    float* out_x = (float*)d_out;
    float* out_m = (float*)d_out + 8388608;

    float*  wgt  = (float*)d_ws;
    __bf16* xh   = (__bf16*)((char*)d_ws + 4718592);
    __bf16* mh   = (__bf16*)((char*)d_ws + 21495808);
    __bf16* x2h  = mh;                              // sequential live ranges
    __bf16* wbase = (__bf16*)((char*)d_ws + 38273024);
    __bf16* wb_c1 = wbase;             // [9][64][64]    36864
    __bf16* wb_c2 = wbase + 36864;     //                36864
    __bf16* wb_F1 = wbase + 73728;     // [25][96][64]  153600
    __bf16* wb_F2 = wbase + 227328;    //               153600

    __bf16* maska_h = (__bf16*)out_x;               // lower 16.78 MB
    __bf16* xa_h    = (__bf16*)out_x + 8388608;     // upper 16.78 MB
    __bf16* x1_h    = (__bf16*)out_m;               // lower 16.78 MB

    dim3 blk(256);
    dim3 gconv(16, 16, 2);
    dim3 gpix(512);

    // 0. layout conversion + weight prep
    k_cvt<<<gpix, blk, 0, stream>>>(x,    xh);
    k_cvt<<<gpix, blk, 0, stream>>>(mask, mh);
    k_prep3<<<144, blk, 0, stream>>>(c1_w, wb_c1);
    k_prep3<<<144, blk, 0, stream>>>(c2_w, wb_c2);
    k_prepF<<<600, blk, 0, stream>>>(mt1_w, aw1_w, wb_F1);
    k_prepF<<<600, blk, 0, stream>>>(mt2_w, aw2_w, wb_F2);

    // 1. F1(mh): maska = lrelu(mt1) -> maska_h (bf16), weight1 = aw1 -> wgt
    k_mconv<5,5,1,0><<<gconv, blk, 0, stream>>>(mh, wb_F1, mt1_b, aw1_b,
                                                nullptr, maska_h, wgt);
    // 2. x1 = conv3x3(xh, c1) -> x1_h (bf16, out_m scratch)
    k_mconv<3,4,0,0><<<gconv, blk, 0, stream>>>(xh, wb_c1, c1_b, nullptr,
                                                nullptr, x1_h, nullptr);
    // 3. xa = lrelu(ada(wgt, x1)) -> xa_h (bf16, out_x upper scratch)
    k_ada<0><<<gpix, blk, 0, stream>>>(wgt, x1_h, nullptr, xa_h);
    // 4. F2(maska_h): final mask = lrelu(mt2) -> out_m (f32), weight2 -> wgt
    k_mconv<5,5,1,1><<<gconv, blk, 0, stream>>>(maska_h, wb_F2, mt2_b, aw2_b,
                                                out_m, nullptr, wgt);
    // 5. x2 = conv3x3(xa_h, c2) -> x2h (bf16, ws)
    k_mconv<3,4,0,0><<<gconv, blk, 0, stream>>>(xa_h, wb_c2, c2_b, nullptr,
                                                nullptr, x2h, nullptr);
    // 6. res = conv1x1(xh) -> out_x (f32, clobbers dead scratch)
    k_conv1x1<<<gpix, blk, 0, stream>>>(xh, cr_w, cr_b, out_x);
    // 7. out_x = lrelu(ada(wgt, x2)) + res
    k_ada<1><<<gpix, blk, 0, stream>>>(wgt, x2h, out_x, nullptr);
}